// Round 1
// baseline (1189.930 us; speedup 1.0000x reference)
//
#include <hip/hip_runtime.h>

// LocalConvolution: out[b,o,i,j] = sum_{c,u,v} x[b,c,i+u,j+v] * w[i,j,o,c,u,v]
// x: [64,64,32,32] f32 ; w: [28,28,128,64,5,5] f32 (642 MB, streamed once) ;
// out: [64,128,28,28] f32.
// Strategy: per-position GEMM M=64,N=128,K=1600 with bf16 MFMA (in-flight
// fp32->bf16 cvt), weights direct global->reg (k-contiguous B^T layout),
// x patch staged in LDS per 64-k chunk. Memory-bound: floor ~109 us.

typedef __attribute__((ext_vector_type(8))) short bf16x8;
typedef __attribute__((ext_vector_type(4))) float f32x4;

__device__ __forceinline__ unsigned short f2bf(float f) {
    unsigned int u = __float_as_uint(f);
    u = (u + 0x7fffu + ((u >> 16) & 1u)) >> 16;   // round-to-nearest-even
    return (unsigned short)u;
}

__global__ __launch_bounds__(256, 3) void lconv_mfma(
    const float* __restrict__ x,
    const float* __restrict__ wgt,
    float* __restrict__ out)
{
    constexpr int K   = 1600;   // C*KH*KW = 64*5*5
    constexpr int KC  = 64;     // k-chunk per iteration (2 MFMA k-steps)
    constexpr int LDK = KC + 8; // +16B pad: distributes ds_read_b128 across banks
    constexpr int O   = 128;
    constexpr int POS = 784;    // 28*28

    __shared__ unsigned short As[64][LDK]; // 9216 B

    const int bx = blockIdx.x;
    // XCD swizzle: consecutive positions (same output cache lines) on same XCD
    const int g = (bx & 7) * 98 + (bx >> 3);   // 784 = 8 * 98
    const int i = g / 28;
    const int j = g - i * 28;

    const int t    = threadIdx.x;
    const int lane = t & 63;
    const int wv   = t >> 6;     // wave 0..3 -> o range [32w, 32w+32)
    const int l15  = lane & 15;
    const int quad = lane >> 4;

    // x strides: b:65536, c:1024, h:32, w:1 ; fold (i,j) into base
    const float* xbase = x + i * 32 + j;
    // staging role: thread handles b = t>>2, k sub-range (t&3)*16 .. +16
    const int sb = t >> 2;
    const int sk = (t & 3) * 16;
    const float* xrow = xbase + sb * 65536;

    const float* wpos = wgt + (size_t)g * (size_t)(O * K);

    f32x4 acc[4][2];
#pragma unroll
    for (int mt = 0; mt < 4; ++mt)
#pragma unroll
        for (int nt = 0; nt < 2; ++nt)
            acc[mt][nt] = (f32x4)0.f;

    for (int kb = 0; kb < K; kb += KC) {
        // ---- stage A chunk: x patch [64 b][64 k] -> bf16 LDS ----
        unsigned int pk[8];
#pragma unroll
        for (int e = 0; e < 16; e += 2) {
            int k0 = kb + sk + e;
            int c0 = k0 / 25, r0 = k0 - 25 * c0;
            int u0 = r0 / 5,  v0 = r0 - 5 * u0;
            int k1 = k0 + 1;
            int c1 = k1 / 25, r1 = k1 - 25 * c1;
            int u1 = r1 / 5,  v1 = r1 - 5 * u1;
            float f0 = xrow[c0 * 1024 + u0 * 32 + v0];
            float f1 = xrow[c1 * 1024 + u1 * 32 + v1];
            pk[e >> 1] = (unsigned int)f2bf(f0) | ((unsigned int)f2bf(f1) << 16);
        }
        {
            uint4 q0 = make_uint4(pk[0], pk[1], pk[2], pk[3]);
            uint4 q1 = make_uint4(pk[4], pk[5], pk[6], pk[7]);
            *(uint4*)&As[sb][sk]     = q0;
            *(uint4*)&As[sb][sk + 8] = q1;
        }
        __syncthreads();

        // ---- compute: 2 k-steps of 32, 4 m-tiles x 2 n-tiles ----
#pragma unroll
        for (int kk = 0; kk < 2; ++kk) {
            bf16x8 bfr[2];
#pragma unroll
            for (int nt = 0; nt < 2; ++nt) {
                const int o = wv * 32 + nt * 16 + l15;
                const float* wp = wpos + (size_t)o * K + (kb + kk * 32 + quad * 8);
                f32x4 w0 = *(const f32x4*)wp;
                f32x4 w1 = *(const f32x4*)(wp + 4);
                bf16x8 bv;
                bv[0] = (short)f2bf(w0[0]); bv[1] = (short)f2bf(w0[1]);
                bv[2] = (short)f2bf(w0[2]); bv[3] = (short)f2bf(w0[3]);
                bv[4] = (short)f2bf(w1[0]); bv[5] = (short)f2bf(w1[1]);
                bv[6] = (short)f2bf(w1[2]); bv[7] = (short)f2bf(w1[3]);
                bfr[nt] = bv;
            }
#pragma unroll
            for (int mt = 0; mt < 4; ++mt) {
                bf16x8 av = *(const bf16x8*)&As[mt * 16 + l15][kk * 32 + quad * 8];
#pragma unroll
                for (int nt = 0; nt < 2; ++nt)
                    acc[mt][nt] = __builtin_amdgcn_mfma_f32_16x16x32_bf16(
                        av, bfr[nt], acc[mt][nt], 0, 0, 0);
            }
        }
        __syncthreads();
    }

    // ---- epilogue: D[m=quad*4+r][n=l15] -> out[b][o][g] ----
#pragma unroll
    for (int mt = 0; mt < 4; ++mt) {
#pragma unroll
        for (int nt = 0; nt < 2; ++nt) {
            const int o = wv * 32 + nt * 16 + l15;
#pragma unroll
            for (int r = 0; r < 4; ++r) {
                const int b = mt * 16 + quad * 4 + r;
                out[((size_t)b * O + o) * POS + g] = acc[mt][nt][r];
            }
        }
    }
}

extern "C" void kernel_launch(void* const* d_in, const int* in_sizes, int n_in,
                              void* d_out, int out_size, void* d_ws, size_t ws_size,
                              hipStream_t stream) {
    const float* x   = (const float*)d_in[0];
    const float* wgt = (const float*)d_in[1];
    float* out       = (float*)d_out;
    lconv_mfma<<<784, 256, 0, stream>>>(x, wgt, out);
}